// Round 1
// baseline (296.156 us; speedup 1.0000x reference)
//
#include <hip/hip_runtime.h>
#include <math.h>

// Problem constants
#define BB 32
#define CC 21
#define TT 512
#define LL 336
#define FREQ 257          // TT/2 + 1
#define NBC (BB*CC)       // 672
#define WROW (FREQ*TT)    // 131584 floats per head_w row

__device__ __constant__ float kAngStep = 6.28318530717958647692f / 512.0f; // 2*pi/T

// ---------------------------------------------------------------------------
// K0: per-(b,c) mean / std.  One wave per row; grid = 672/4 blocks x 256 thr.
// ---------------------------------------------------------------------------
__global__ __launch_bounds__(256) void k0_stats(const float* __restrict__ z,
                                                float* __restrict__ meanv,
                                                float* __restrict__ stdv) {
    int row  = blockIdx.x * 4 + (threadIdx.x >> 6);
    int lane = threadIdx.x & 63;
    const float* zr = z + (size_t)row * TT;
    float s = 0.f, sq = 0.f;
#pragma unroll
    for (int j = 0; j < 8; ++j) {
        float v = zr[lane + 64 * j];
        s += v; sq += v * v;
    }
#pragma unroll
    for (int off = 32; off; off >>= 1) {
        s  += __shfl_xor(s,  off);
        sq += __shfl_xor(sq, off);
    }
    if (lane == 0) {
        float mu  = s * (1.0f / TT);
        float var = sq * (1.0f / TT) - mu * mu;
        meanv[row] = mu;
        stdv[row]  = sqrtf(var + 1e-5f);
    }
}

// ---------------------------------------------------------------------------
// K1: THE streaming kernel.  A[p][l] = sum_t W[l,p,t] cos(2pi p t/T)
//                            Bs[p][l] = sum_t W[l,p,t] sin(2pi p t/T)
// One wave per (l,p).  Lanes cover t = 4*lane..4*lane+3 and +256 (the +256
// chunk folds in with sign (-1)^p).  2x float4 loads per lane = 2KB/wave,
// perfectly coalesced.  Trig: 2 sincos + 3 in-register rotations per lane.
// grid = 336 * 65 blocks x 256 threads (4 waves; p = ptile*4 + wave).
// ---------------------------------------------------------------------------
__global__ __launch_bounds__(256) void k1_ab(const float* __restrict__ hw,
                                             float* __restrict__ A,
                                             float* __restrict__ Bsm) {
    int bid  = blockIdx.x;
    int l    = bid / 65;
    int pt   = bid - l * 65;
    int w    = threadIdx.x >> 6;
    int p    = pt * 4 + w;
    if (p >= FREQ) return;
    int lane = threadIdx.x & 63;

    const float4* src = (const float4*)(hw + (size_t)l * WROW + (size_t)p * TT);
    float4 w1 = src[lane];        // t = 4*lane .. 4*lane+3
    float4 w2 = src[lane + 64];   // t = 256 + 4*lane ..

    float sgn = (p & 1) ? -1.0f : 1.0f;   // cos/sin(theta + pi*p) = (-1)^p * ...
    float u0 = w1.x + sgn * w2.x;
    float u1 = w1.y + sgn * w2.y;
    float u2 = w1.z + sgn * w2.z;
    float u3 = w1.w + sgn * w2.w;

    // base angle for t0 = 4*lane (use mod-T periodicity to keep arg small+exact)
    int   k0 = (p * (lane * 4)) & 511;
    float a0 = (float)k0 * kAngStep;
    float c0, s0; sincosf(a0, &s0, &c0);
    float ad = (float)p * kAngStep;       // step per t
    float cd, sd; sincosf(ad, &sd, &cd);

    float c1 = c0 * cd - s0 * sd,  s1 = s0 * cd + c0 * sd;
    float c2 = c1 * cd - s1 * sd,  s2 = s1 * cd + c1 * sd;
    float c3 = c2 * cd - s2 * sd,  s3 = s2 * cd + c2 * sd;

    float accA = u0 * c0 + u1 * c1 + u2 * c2 + u3 * c3;
    float accB = u0 * s0 + u1 * s1 + u2 * s2 + u3 * s3;

#pragma unroll
    for (int off = 32; off; off >>= 1) {
        accA += __shfl_xor(accA, off);
        accB += __shfl_xor(accB, off);
    }
    if (lane == 0) {
        A  [p * LL + l] = accA;
        Bsm[p * LL + l] = accB;
    }
}

// ---------------------------------------------------------------------------
// K2: K[t][l] = (2/T) * [0.5*A[0][l] + sum_{p=1..256} cos(2pi p t/T)A[p][l]
//                                              + sin(2pi p t/T)Bs[p][l]]
// Block per l (336), thread per t (512).  A/Bs loads are wave-uniform ->
// scalar loads.  Per-thread rotation recurrence over p, 2 interleaved states
// for ILP.  Also block-reduces S[l] = sum_t K[t][l].
// ---------------------------------------------------------------------------
__global__ __launch_bounds__(512) void k2_kbuild(const float* __restrict__ A,
                                                 const float* __restrict__ Bsm,
                                                 float* __restrict__ Km,
                                                 float* __restrict__ S) {
    int l = blockIdx.x;
    int t = threadIdx.x;            // 0..511
    const float* Al = A   + l;
    const float* Bl = Bsm + l;

    float dc, ds; sincosf((float)t * kAngStep, &ds, &dc);  // step per p
    // two states: p=1 and p=2, both stepping by 2*delta
    float c1 = dc, s1 = ds;
    float c2 = dc * dc - ds * ds;
    float s2 = 2.0f * dc * ds;
    float cd2 = c2, sd2 = s2;

    float acc1 = 0.5f * Al[0];
    float acc2 = 0.0f;
#pragma unroll 4
    for (int p = 1; p <= 255; p += 2) {
        acc1 += c1 * Al[p * LL]       + s1 * Bl[p * LL];
        acc2 += c2 * Al[(p + 1) * LL] + s2 * Bl[(p + 1) * LL];
        float nc1 = c1 * cd2 - s1 * sd2; s1 = s1 * cd2 + c1 * sd2; c1 = nc1;
        float nc2 = c2 * cd2 - s2 * sd2; s2 = s2 * cd2 + c2 * sd2; c2 = nc2;
    }
    float kval = (acc1 + acc2) * (2.0f / TT);
    Km[t * LL + l] = kval;

    // S[l] = sum over t
    float ss = kval;
#pragma unroll
    for (int off = 32; off; off >>= 1) ss += __shfl_xor(ss, off);
    __shared__ float red[8];
    if ((t & 63) == 0) red[t >> 6] = ss;
    __syncthreads();
    if (t == 0) {
        float tot = 0.f;
#pragma unroll
        for (int j = 0; j < 8; ++j) tot += red[j];
        S[l] = tot;
    }
}

// ---------------------------------------------------------------------------
// K3: D[bc][l] = sum_t z[bc][t] * K[t][l], then fused un-affine epilogue:
//   out = (w*(D - mu*S) + sigma*(b*S + hb - b)) / (w + 1e-10) + mu
// Block = 4 bc-rows x 384 threads (l = tid).  K reads coalesced (1344B/row),
// z reads wave-uniform -> scalar loads.
// ---------------------------------------------------------------------------
__global__ __launch_bounds__(384) void k3_gemm(const float* __restrict__ z,
                                               const float* __restrict__ Km,
                                               const float* __restrict__ S,
                                               const float* __restrict__ meanv,
                                               const float* __restrict__ stdv,
                                               const float* __restrict__ aw,
                                               const float* __restrict__ ab,
                                               const float* __restrict__ hb,
                                               float* __restrict__ out) {
    int l = threadIdx.x;
    if (l >= LL) return;
    int bc0 = blockIdx.x * 4;
    const float* z0 = z + (size_t)bc0 * TT;
    const float* Kl = Km + l;

    float d0 = 0.f, d1 = 0.f, d2 = 0.f, d3 = 0.f;
#pragma unroll 8
    for (int t = 0; t < TT; ++t) {
        float k = Kl[t * LL];
        d0 += z0[t]           * k;
        d1 += z0[TT + t]      * k;
        d2 += z0[2 * TT + t]  * k;
        d3 += z0[3 * TT + t]  * k;
    }
    float Sl = S[l], hbl = hb[l];
    float d[4] = {d0, d1, d2, d3};
#pragma unroll
    for (int j = 0; j < 4; ++j) {
        int bc = bc0 + j;
        int c  = bc % CC;
        float mu = meanv[bc], sg = stdv[bc];
        float w  = aw[c],     b  = ab[c];
        out[(size_t)bc * LL + l] =
            (w * (d[j] - mu * Sl) + sg * (b * Sl + hbl - b)) / (w + 1e-10f) + mu;
    }
}

// ---------------------------------------------------------------------------
extern "C" void kernel_launch(void* const* d_in, const int* in_sizes, int n_in,
                              void* d_out, int out_size, void* d_ws, size_t ws_size,
                              hipStream_t stream) {
    const float* z  = (const float*)d_in[0];
    const float* aw = (const float*)d_in[1];
    const float* ab = (const float*)d_in[2];
    const float* hw = (const float*)d_in[3];
    const float* hb = (const float*)d_in[4];
    float* out = (float*)d_out;

    float* ws    = (float*)d_ws;
    float* meanv = ws;                       // 672
    float* stdv  = ws + NBC;                 // 672
    float* A     = stdv + NBC;               // 257*336 = 86352
    float* Bsm   = A + FREQ * LL;            // 86352
    float* Km    = Bsm + FREQ * LL;          // 512*336 = 172032
    float* S     = Km + TT * LL;             // 336
    // total ~1.39 MB of d_ws

    k0_stats <<<NBC / 4, 256, 0, stream>>>(z, meanv, stdv);
    k1_ab    <<<LL * 65, 256, 0, stream>>>(hw, A, Bsm);
    k2_kbuild<<<LL,      512, 0, stream>>>(A, Bsm, Km, S);
    k3_gemm  <<<NBC / 4, 384, 0, stream>>>(z, Km, S, meanv, stdv, aw, ab, hb, out);
}